// Round 23
// baseline (11.025 us; speedup 1.0000x reference)
//
#include <hip/hip_runtime.h>

// PSRoIPool round 23 — RECIPROCAL-MULTIPLY BIN (XLA strength reduction).
// Grid proof: all faithful Δ/7 evaluations give bit-equal windows (non-exact
// boundaries ≥1/112 from integers; exact ones compute exactly N in every
// precision). Ref windows DIFFER anyway => ref's bin ≠ fl(Δ/7). The standard
// compiler transform div-by-const -> mul-by-reciprocal gives
// bin = Δ·fl32(1/7) = (Δ/7)(1+4.5e-8) (fl32(1/7) is ABOVE 1/7), so exact-
// integer END boundaries land at N+eps -> ceil N+1: one phantom row/col on
// the sparse set {7|16Δ}. Fits all measurements: cnt-1 spared (r13), end-bin
// p=6 mostly clip-saturated at ye=38 -> milder (r16/r19), dev ∝ 1/size both
// signs (r9..r21), invariance across my /7 variants (r1-r5,r17), every
// convention edit worse (r6,r8,r10,r12,r18,r20,r22).

#pragma clang fp contract(off)

#define PS 7
#define DD 10
#define CC 490
#define HH 38
#define WW 38

__device__ __forceinline__ float mul_add_strict_f32(float a, float b, float c) {
#pragma clang fp contract(off)
    float p = a * b;
    asm volatile("" : "+v"(p));   // block fma contraction
    return p + c;
}

__global__ __launch_bounds__(256) void psroi_pool_kernel(
    const float* __restrict__ feat,
    const float* __restrict__ rois,
    float* __restrict__ out,
    int total)
{
#pragma clang fp contract(off)
    int idx = blockIdx.x * blockDim.x + threadIdx.x;
    if (idx >= total) return;

    int pw = idx % PS;
    int ph = (idx / PS) % PS;
    int d  = (idx / (PS * PS)) % DD;
    int r  = idx / (PS * PS * DD);

    const float* roi = rois + (size_t)r * 5;
    int b = (int)roi[0];

    float xs = rintf(roi[1]) * 0.0625f;
    float ys = rintf(roi[2]) * 0.0625f;
    float xe = rintf(roi[3] + 1.0f) * 0.0625f;
    float ye = rintf(roi[4] + 1.0f) * 0.0625f;

    float roi_w = fmaxf(xe - xs, 0.1f);
    float roi_h = fmaxf(ye - ys, 0.1f);

    // RECIPROCAL MULTIPLY: bin = roi * fl32(1/7)  (NOT __fdiv_rn(roi,7))
    const float RECIP7 = 1.0f / 7.0f;   // compile-time fl32(1/7) = 0.14285714924...
    float bin_w = roi_w * RECIP7;
    float bin_h = roi_h * RECIP7;

    float hs_f = floorf(mul_add_strict_f32((float)ph,       bin_h, ys));
    float he_f = ceilf (mul_add_strict_f32((float)(ph + 1), bin_h, ys));
    float ws_f = floorf(mul_add_strict_f32((float)pw,       bin_w, xs));
    float we_f = ceilf (mul_add_strict_f32((float)(pw + 1), bin_w, xs));

    int hstart = (int)fminf(fmaxf(hs_f, 0.0f), (float)HH);
    int hend   = (int)fminf(fmaxf(he_f, 0.0f), (float)HH);
    int wstart = (int)fminf(fmaxf(ws_f, 0.0f), (float)WW);
    int wend   = (int)fminf(fmaxf(we_f, 0.0f), (float)WW);

    int c = (d * PS + ph) * PS + pw;
    const float* fp = feat + ((size_t)b * CC + c) * (HH * WW);

    float sum = 0.0f;
    for (int h = hstart; h < hend; ++h) {
        const float* row = fp + h * WW;
        for (int w = wstart; w < wend; ++w) {
            sum += row[w];
        }
    }

    int cnt = (hend - hstart) * (wend - wstart);
    out[idx] = (cnt > 0) ? (sum / (float)cnt) : 0.0f;
}

extern "C" void kernel_launch(void* const* d_in, const int* in_sizes, int n_in,
                              void* d_out, int out_size, void* d_ws, size_t ws_size,
                              hipStream_t stream) {
    const float* feat = (const float*)d_in[0];
    const float* rois = (const float*)d_in[1];
    float* out = (float*)d_out;

    int total = out_size;  // 125440
    int block = 256;
    int grid = (total + block - 1) / block;
    psroi_pool_kernel<<<grid, block, 0, stream>>>(feat, rois, out, total);
}